// Round 4
// baseline (849.087 us; speedup 1.0000x reference)
//
#include <hip/hip_runtime.h>

typedef unsigned short u16;
typedef unsigned int u32;
typedef float f32x4 __attribute__((ext_vector_type(4)));
typedef float f32x16 __attribute__((ext_vector_type(16)));
typedef __bf16 bf16x8 __attribute__((ext_vector_type(8)));
typedef u32 u32x4 __attribute__((ext_vector_type(4)));

__device__ __forceinline__ u16 f2bf(float f) {
  u32 u = __builtin_bit_cast(u32, f);
  u32 r = (u + 0x7fffu + ((u >> 16) & 1u)) >> 16;
  return (u16)r;
}

__device__ __forceinline__ u32 pk2bf(float lo, float hi_) {
  u32 r;
  asm("v_cvt_pk_bf16_f32 %0, %1, %2" : "=v"(r) : "v"(lo), "v"(hi_));
  return r;
}

__device__ __forceinline__ void plswap(u32 &a, u32 &b) {
#if __has_builtin(__builtin_amdgcn_permlane32_swap)
  auto r = __builtin_amdgcn_permlane32_swap(a, b, false, false);
  a = r[0]; b = r[1];
#else
  asm volatile("v_permlane32_swap_b32 %0, %1" : "+v"(a), "+v"(b));
#endif
}

__device__ __forceinline__ float xhalf_max(float x) {
  u32 a = __builtin_bit_cast(u32, x), b = a;
  plswap(a, b);
  return fmaxf(__builtin_bit_cast(float, a), __builtin_bit_cast(float, b));
}
__device__ __forceinline__ float xhalf_sum(float x) {
  u32 a = __builtin_bit_cast(u32, x), b = a;
  plswap(a, b);
  return __builtin_bit_cast(float, a) + __builtin_bit_cast(float, b);
}

// async global->LDS, 16B per lane (dest = uniform base + lane*16)
__device__ __forceinline__ void gll16(const u16* g, u16* l) {
  __builtin_amdgcn_global_load_lds(
      (const __attribute__((address_space(1))) void*)g,
      (__attribute__((address_space(3))) void*)l, 16, 0, 0);
}

// ---------------- fp32 -> bf16 conversion (x, Wq|Wkv concat, Wo) ----------------
__global__ __launch_bounds__(256) void cvt_kernel(
    const float4* __restrict__ x, const float4* __restrict__ wq,
    const float4* __restrict__ wkv, const float4* __restrict__ wo,
    uint2* __restrict__ xb, uint2* __restrict__ wqkvb, uint2* __restrict__ wob) {
  long i = (long)blockIdx.x * 256 + threadIdx.x;
  const float4* src; uint2* dst; long off;
  if (i < 1048576)      { src = x;   dst = xb;             off = i; }
  else if (i < 1310720) { src = wq;  dst = wqkvb;          off = i - 1048576; }
  else if (i < 1441792) { src = wkv; dst = wqkvb + 262144; off = i - 1310720; }
  else                  { src = wo;  dst = wob;            off = i - 1441792; }
  float4 v = src[off];
  uint2 o;
  o.x = ((u32)f2bf(v.y) << 16) | (u32)f2bf(v.x);
  o.y = ((u32)f2bf(v.w) << 16) | (u32)f2bf(v.z);
  dst[off] = o;
}

// ---------------- m97-structure 128x128 bf16 GEMM core (C = A * W^T) ----------------
// BK=32, linear [128][32] LDS tiles, global_load_lds dwordx4 staging.
// 256 threads = 4 waves (2x2), each wave 64x64 = 4x4 frags of 16x16x32 MFMA.
__device__ __forceinline__ void gemm_core(
    const u16* __restrict__ A, const u16* __restrict__ W, const int K,
    f32x4 acc[4][4], u16* As, u16* Ws) {
  const int t = threadIdx.x, lane = t & 63, w = t >> 6;
  const int wm = (w >> 1) * 64, wn = (w & 1) * 64;
  const long bm = (long)blockIdx.x * 128, bn = (long)blockIdx.y * 128;
  const int cc = lane & 15, kg8 = (lane >> 4) * 8;

  // staging geometry: one gll16 per wave covers 16 rows (4 lanes/row, 8 u16/lane)
  const int srow = w * 32 + (lane >> 2);
  const int scol = (lane & 3) * 8;
  const u16* Ag0 = &A[(bm + srow) * (long)K + scol];
  const u16* Ag1 = Ag0 + 16 * (long)K;
  const u16* Wg0 = &W[(bn + srow) * (long)K + scol];
  const u16* Wg1 = Wg0 + 16 * (long)K;
  u16* Al0 = As + (w * 32) * 32;
  u16* Al1 = Al0 + 16 * 32;
  u16* Wl0 = Ws + (w * 32) * 32;
  u16* Wl1 = Wl0 + 16 * 32;

#pragma unroll
  for (int i = 0; i < 4; i++)
#pragma unroll
    for (int j = 0; j < 4; j++) acc[i][j] = f32x4{0.f, 0.f, 0.f, 0.f};

  for (int k0 = 0; k0 < K; k0 += 32) {
    gll16(Ag0 + k0, Al0);
    gll16(Ag1 + k0, Al1);
    gll16(Wg0 + k0, Wl0);
    gll16(Wg1 + k0, Wl1);
    __syncthreads();   // drains vmcnt (gll) before any wave reads LDS
    bf16x8 af[4], wf[4];
#pragma unroll
    for (int i = 0; i < 4; i++) af[i] = *(const bf16x8*)&As[(wm + i * 16 + cc) * 32 + kg8];
#pragma unroll
    for (int j = 0; j < 4; j++) wf[j] = *(const bf16x8*)&Ws[(wn + j * 16 + cc) * 32 + kg8];
#pragma unroll
    for (int i = 0; i < 4; i++)
#pragma unroll
      for (int j = 0; j < 4; j++)
        acc[i][j] = __builtin_amdgcn_mfma_f32_16x16x32_bf16(af[i], wf[j], acc[i][j], 0, 0, 0);
    __syncthreads();
  }
}

// ---------------- GEMM1: qkv projection + routing epilogue ----------------
// Q is pre-scaled by SCALE*log2e so attention works in exp2 domain.
__global__ __launch_bounds__(256) void gemm_qkv_kernel(
    const u16* __restrict__ A, const u16* __restrict__ W,
    u16* __restrict__ Qb, u16* __restrict__ Kb, u16* __restrict__ VTb) {
  __shared__ __align__(16) u16 As[128 * 32];
  __shared__ __align__(16) u16 Ws[128 * 32];
  f32x4 acc[4][4];
  gemm_core(A, W, 1024, acc, As, Ws);
  const int t = threadIdx.x, lane = t & 63, w = t >> 6;
  const int wm = (w >> 1) * 64, wn = (w & 1) * 64;
  const int bm = blockIdx.x * 128, bn = blockIdx.y * 128;
  const int rr = (lane >> 4) * 4, cc = lane & 15;
#pragma unroll
  for (int i = 0; i < 4; i++)
#pragma unroll
    for (int jf = 0; jf < 4; jf++)
#pragma unroll
      for (int j = 0; j < 4; j++) {
        int m = bm + wm + i * 16 + rr + j;
        int n = bn + wn + jf * 16 + cc;
        float v = acc[i][jf][j];
        if (n < 1024) {
          Qb[(long)m * 1024 + n] = f2bf(v * 0.18033688011112043f);  // 0.125*log2(e)
        } else {
          int c = n - 1024, g = c >> 7, rm = c & 127;
          int b = m >> 11, pos = m & 2047;
          long base = (long)(b * 4 + g);
          if (rm < 64) Kb[(base * 2048 + pos) * 64 + rm] = f2bf(v);
          else         VTb[(base * 64 + (rm - 64)) * 2048 + pos] = f2bf(v);
        }
      }
}

// ---------------- GEMM2: output projection, fp32 out ----------------
__global__ __launch_bounds__(256) void gemm_out_kernel(
    const u16* __restrict__ A, const u16* __restrict__ W, float* __restrict__ out) {
  __shared__ __align__(16) u16 As[128 * 32];
  __shared__ __align__(16) u16 Ws[128 * 32];
  f32x4 acc[4][4];
  gemm_core(A, W, 1024, acc, As, Ws);
  const int t = threadIdx.x, lane = t & 63, w = t >> 6;
  const int wm = (w >> 1) * 64, wn = (w & 1) * 64;
  const int bm = blockIdx.x * 128, bn = blockIdx.y * 128;
  const int rr = (lane >> 4) * 4, cc = lane & 15;
#pragma unroll
  for (int i = 0; i < 4; i++)
#pragma unroll
    for (int jf = 0; jf < 4; jf++)
#pragma unroll
      for (int j = 0; j < 4; j++) {
        int m = bm + wm + i * 16 + rr + j;
        int n = bn + wn + jf * 16 + cc;
        out[(long)m * 1024 + n] = acc[i][jf][j];
      }
}

// ---------------- flash attention (causal + ALiBi, GQA) ----------------
// Swapped-operand 32x32x16, in-register softmax, descending key iteration with
// defer-max (T13), two-phase cross-wave combine (LDS 19.5KB -> 8 blocks/CU).
__global__ __launch_bounds__(256, 8) void attn_kernel(
    const u16* __restrict__ Q, const u16* __restrict__ Kb,
    const u16* __restrict__ VTb, u16* __restrict__ AT) {
  __shared__ __align__(16) float Ol[4][32][36];
  __shared__ float ml[4][2][32];

  const int t = threadIdx.x, lane = t & 63, w = t >> 6;
  const int qt = 63 - (int)blockIdx.x;   // LPT: longest blocks first
  const int h = blockIdx.y, b = blockIdx.z;
  const int g = h >> 2;
  const int lam = lane & 31, hi = lane >> 5;
  const int qrow0 = qt * 32;
  const int kblocks = (qrow0 + 95) >> 6;

  const u16* Qrow = Q + ((long)(b * 2048 + qrow0 + lam)) * 1024 + h * 64 + hi * 8;
  bf16x8 qf0 = *(const bf16x8*)(Qrow);
  bf16x8 qf1 = *(const bf16x8*)(Qrow + 16);
  bf16x8 qf2 = *(const bf16x8*)(Qrow + 32);
  bf16x8 qf3 = *(const bf16x8*)(Qrow + 48);

  const u16* Kg = Kb  + ((long)(b * 4 + g)) * 2048 * 64;
  const u16* Vg = VTb + ((long)(b * 4 + g)) * 64 * 2048;

  f32x16 zv;
#pragma unroll
  for (int i = 0; i < 16; i++) zv[i] = 0.f;
  f32x16 acc0 = zv, acc1 = zv;
  float m = -1e30f, lsum = 0.f;

  const float slope2 = exp2f(-0.5f * (float)(h + 1)) * 1.44269504f;
  const float fqr = (float)(qrow0 + lam);

  auto qk_tile = [&](int koff) -> f32x16 {
    const u16* Ka = Kg + (long)(koff + lam) * 64 + hi * 8;
    bf16x8 k0 = *(const bf16x8*)(Ka);
    bf16x8 k1 = *(const bf16x8*)(Ka + 16);
    bf16x8 k2 = *(const bf16x8*)(Ka + 32);
    bf16x8 k3 = *(const bf16x8*)(Ka + 48);
    f32x16 s = zv;
    s = __builtin_amdgcn_mfma_f32_32x32x16_bf16(k0, qf0, s, 0, 0, 0);
    s = __builtin_amdgcn_mfma_f32_32x32x16_bf16(k1, qf1, s, 0, 0, 0);
    s = __builtin_amdgcn_mfma_f32_32x32x16_bf16(k2, qf2, s, 0, 0, 0);
    s = __builtin_amdgcn_mfma_f32_32x32x16_bf16(k3, qf3, s, 0, 0, 0);
    float kb0 = (float)(koff + 4 * hi) - fqr;
    if (koff + 31 > qrow0) {
#pragma unroll
      for (int r = 0; r < 16; r++) {
        float d = kb0 + (float)((r & 3) + 8 * (r >> 2));
        s[r] = (d > 0.f) ? -1e30f : s[r] + slope2 * d;
      }
    } else {
#pragma unroll
      for (int r = 0; r < 16; r++)
        s[r] += slope2 * (kb0 + (float)((r & 3) + 8 * (r >> 2)));
    }
    return s;
  };

  auto pv_tile = [&](const f32x16 &p, int koff) {
    u32 wd[8];
#pragma unroll
    for (int i = 0; i < 8; i++) wd[i] = pk2bf(p[2 * i], p[2 * i + 1]);
    plswap(wd[0], wd[2]); plswap(wd[1], wd[3]);
    plswap(wd[4], wd[6]); plswap(wd[5], wd[7]);
    bf16x8 pf0 = __builtin_bit_cast(bf16x8, u32x4{wd[0], wd[1], wd[2], wd[3]});
    bf16x8 pf1 = __builtin_bit_cast(bf16x8, u32x4{wd[4], wd[5], wd[6], wd[7]});
    const u16* Va = Vg + (long)lam * 2048 + koff + hi * 8;
    bf16x8 v00 = *(const bf16x8*)(Va);
    bf16x8 v01 = *(const bf16x8*)(Va + 16);
    bf16x8 v10 = *(const bf16x8*)(Va + 32 * 2048);
    bf16x8 v11 = *(const bf16x8*)(Va + 32 * 2048 + 16);
    acc0 = __builtin_amdgcn_mfma_f32_32x32x16_bf16(v00, pf0, acc0, 0, 0, 0);
    acc0 = __builtin_amdgcn_mfma_f32_32x32x16_bf16(v01, pf1, acc0, 0, 0, 0);
    acc1 = __builtin_amdgcn_mfma_f32_32x32x16_bf16(v10, pf0, acc1, 0, 0, 0);
    acc1 = __builtin_amdgcn_mfma_f32_32x32x16_bf16(v11, pf1, acc1, 0, 0, 0);
  };

  // descending key iteration: diagonal-most tile first -> running max set early,
  // ALiBi decay makes later (farther) tiles smaller -> defer-max skips rescales.
  const int jb0 = (kblocks > w) ? (w + (((kblocks - 1 - w) >> 2) << 2)) : -1;
  for (int jb = jb0; jb >= 0; jb -= 4) {
    const int kbase = jb * 64;
    f32x16 st0 = qk_tile(kbase);
    f32x16 st1;
    const bool t1v = (kbase + 32 <= qrow0 + 31);
    if (t1v) {
      st1 = qk_tile(kbase + 32);
    } else {
#pragma unroll
      for (int r = 0; r < 16; r++) st1[r] = -1e30f;
    }

    float red[8];
#pragma unroll
    for (int i = 0; i < 8; i++)
      red[i] = fmaxf(fmaxf(st0[i], st0[i + 8]), fmaxf(st1[i], st1[i + 8]));
#pragma unroll
    for (int i = 0; i < 4; i++) red[i] = fmaxf(red[i], red[i + 4]);
    float pm = fmaxf(fmaxf(red[0], red[1]), fmaxf(red[2], red[3]));
    pm = xhalf_max(pm);
    if (!__all(pm <= m + 8.f)) {       // T13 defer-max: P bounded by 2^8
      float mnew = fmaxf(m, pm);
      float al = exp2f(m - mnew);
      m = mnew;
      lsum *= al;
      acc0 *= al;
      acc1 *= al;
    }
#pragma unroll
    for (int r = 0; r < 16; r++) st0[r] = exp2f(st0[r] - m);
#pragma unroll
    for (int r = 0; r < 16; r++) st1[r] = exp2f(st1[r] - m);
    {
      float sr[8];
#pragma unroll
      for (int i = 0; i < 8; i++) sr[i] = (st0[i] + st0[i + 8]) + (st1[i] + st1[i + 8]);
#pragma unroll
      for (int i = 0; i < 4; i++) sr[i] += sr[i + 4];
      float rs = (sr[0] + sr[1]) + (sr[2] + sr[3]);
      lsum += xhalf_sum(rs);
    }

    pv_tile(st0, kbase);
    if (t1v) pv_tile(st1, kbase + 32);
  }

  // ---- two-phase cross-wave combine (halved LDS) ----
#pragma unroll
  for (int rq = 0; rq < 4; rq++)
    *(f32x4*)&Ol[w][lam][8 * rq + 4 * hi] =
        f32x4{acc0[4 * rq], acc0[4 * rq + 1], acc0[4 * rq + 2], acc0[4 * rq + 3]};
  if (hi == 0) { ml[w][0][lam] = m; ml[w][1][lam] = lsum; }
  __syncthreads();

  const int r = t >> 3, c0 = (t & 7) * 4;
  float M = fmaxf(fmaxf(ml[0][0][r], ml[1][0][r]), fmaxf(ml[2][0][r], ml[3][0][r]));
  float sc[4];
  float L = 0.f;
#pragma unroll
  for (int ww = 0; ww < 4; ww++) {
    sc[ww] = exp2f(ml[ww][0][r] - M);
    L += sc[ww] * ml[ww][1][r];
  }
  const float inv = 1.f / L;
  {
    float o[4] = {0.f, 0.f, 0.f, 0.f};
#pragma unroll
    for (int ww = 0; ww < 4; ww++)
#pragma unroll
      for (int i = 0; i < 4; i++) o[i] += sc[ww] * Ol[ww][r][c0 + i];
    uint2 ov;
    ov.x = ((u32)f2bf(o[1] * inv) << 16) | f2bf(o[0] * inv);
    ov.y = ((u32)f2bf(o[3] * inv) << 16) | f2bf(o[2] * inv);
    *(uint2*)&AT[((long)(b * 2048 + qrow0 + r)) * 1024 + h * 64 + c0] = ov;
  }
  __syncthreads();   // Ol reads done; safe to overwrite with acc1
#pragma unroll
  for (int rq = 0; rq < 4; rq++)
    *(f32x4*)&Ol[w][lam][8 * rq + 4 * hi] =
        f32x4{acc1[4 * rq], acc1[4 * rq + 1], acc1[4 * rq + 2], acc1[4 * rq + 3]};
  __syncthreads();
  {
    float o[4] = {0.f, 0.f, 0.f, 0.f};
#pragma unroll
    for (int ww = 0; ww < 4; ww++)
#pragma unroll
      for (int i = 0; i < 4; i++) o[i] += sc[ww] * Ol[ww][r][c0 + i];
    uint2 ov;
    ov.x = ((u32)f2bf(o[1] * inv) << 16) | f2bf(o[0] * inv);
    ov.y = ((u32)f2bf(o[3] * inv) << 16) | f2bf(o[2] * inv);
    *(uint2*)&AT[((long)(b * 2048 + qrow0 + r)) * 1024 + h * 64 + 32 + c0] = ov;
  }
}

// ---------------- launcher ----------------
extern "C" void kernel_launch(void* const* d_in, const int* in_sizes, int n_in,
                              void* d_out, int out_size, void* d_ws, size_t ws_size,
                              hipStream_t stream) {
  const float* x   = (const float*)d_in[0];
  const float* Wq  = (const float*)d_in[1];
  const float* Wkv = (const float*)d_in[2];
  const float* Wo  = (const float*)d_in[3];
  float* out = (float*)d_out;
  char* ws = (char*)d_ws;

  u16* xb    = (u16*)(ws);
  u16* wqkvb = (u16*)(ws + 8388608);
  u16* wob   = (u16*)(ws + 11534336);
  u16* Qb    = (u16*)(ws + 13631488);
  u16* Kb    = (u16*)(ws + 22020096);
  u16* VTb   = (u16*)(ws + 24117248);
  u16* AT    = (u16*)(ws + 26214400);

  cvt_kernel<<<6656, 256, 0, stream>>>(
      (const float4*)x, (const float4*)Wq, (const float4*)Wkv, (const float4*)Wo,
      (uint2*)xb, (uint2*)wqkvb, (uint2*)wob);

  gemm_qkv_kernel<<<dim3(32, 12), 256, 0, stream>>>(xb, wqkvb, Qb, Kb, VTb);

  attn_kernel<<<dim3(64, 16, 2), 256, 0, stream>>>(Qb, Kb, VTb, AT);

  gemm_out_kernel<<<dim3(32, 8), 256, 0, stream>>>(AT, wob, out);
}

// Round 5
// 232.614 us; speedup vs baseline: 3.6502x; 3.6502x over previous
//
#include <hip/hip_runtime.h>

typedef unsigned short u16;
typedef unsigned int u32;
typedef float f32x4 __attribute__((ext_vector_type(4)));
typedef float f32x16 __attribute__((ext_vector_type(16)));
typedef __bf16 bf16x8 __attribute__((ext_vector_type(8)));
typedef u32 u32x4 __attribute__((ext_vector_type(4)));

__device__ __forceinline__ u16 f2bf(float f) {
  u32 u = __builtin_bit_cast(u32, f);
  u32 r = (u + 0x7fffu + ((u >> 16) & 1u)) >> 16;
  return (u16)r;
}

__device__ __forceinline__ u32 pk2bf(float lo, float hi_) {
  u32 r;
  asm("v_cvt_pk_bf16_f32 %0, %1, %2" : "=v"(r) : "v"(lo), "v"(hi_));
  return r;
}

__device__ __forceinline__ void plswap(u32 &a, u32 &b) {
#if __has_builtin(__builtin_amdgcn_permlane32_swap)
  auto r = __builtin_amdgcn_permlane32_swap(a, b, false, false);
  a = r[0]; b = r[1];
#else
  asm volatile("v_permlane32_swap_b32 %0, %1" : "+v"(a), "+v"(b));
#endif
}

__device__ __forceinline__ float xhalf_max(float x) {
  u32 a = __builtin_bit_cast(u32, x), b = a;
  plswap(a, b);
  return fmaxf(__builtin_bit_cast(float, a), __builtin_bit_cast(float, b));
}
__device__ __forceinline__ float xhalf_sum(float x) {
  u32 a = __builtin_bit_cast(u32, x), b = a;
  plswap(a, b);
  return __builtin_bit_cast(float, a) + __builtin_bit_cast(float, b);
}

// async global->LDS, 16B per lane (dest = uniform base + lane*16)
__device__ __forceinline__ void gll16(const u16* g, u16* l) {
  __builtin_amdgcn_global_load_lds(
      (const __attribute__((address_space(1))) void*)g,
      (__attribute__((address_space(3))) void*)l, 16, 0, 0);
}

// ---------------- fp32 -> bf16 conversion (x, Wq|Wkv concat, Wo) ----------------
__global__ __launch_bounds__(256) void cvt_kernel(
    const float4* __restrict__ x, const float4* __restrict__ wq,
    const float4* __restrict__ wkv, const float4* __restrict__ wo,
    uint2* __restrict__ xb, uint2* __restrict__ wqkvb, uint2* __restrict__ wob) {
  long i = (long)blockIdx.x * 256 + threadIdx.x;
  const float4* src; uint2* dst; long off;
  if (i < 1048576)      { src = x;   dst = xb;             off = i; }
  else if (i < 1310720) { src = wq;  dst = wqkvb;          off = i - 1048576; }
  else if (i < 1441792) { src = wkv; dst = wqkvb + 262144; off = i - 1310720; }
  else                  { src = wo;  dst = wob;            off = i - 1441792; }
  float4 v = src[off];
  uint2 o;
  o.x = ((u32)f2bf(v.y) << 16) | (u32)f2bf(v.x);
  o.y = ((u32)f2bf(v.w) << 16) | (u32)f2bf(v.z);
  dst[off] = o;
}

// ---------------- m97-structure 128x128 bf16 GEMM core (C = A * W^T) ----------------
// BK=32, linear [128][32] LDS tiles, global_load_lds dwordx4 staging.
__device__ __forceinline__ void gemm_core(
    const u16* __restrict__ A, const u16* __restrict__ W, const int K,
    f32x4 acc[4][4], u16* As, u16* Ws) {
  const int t = threadIdx.x, lane = t & 63, w = t >> 6;
  const int wm = (w >> 1) * 64, wn = (w & 1) * 64;
  const long bm = (long)blockIdx.x * 128, bn = (long)blockIdx.y * 128;
  const int cc = lane & 15, kg8 = (lane >> 4) * 8;

  const int srow = w * 32 + (lane >> 2);
  const int scol = (lane & 3) * 8;
  const u16* Ag0 = &A[(bm + srow) * (long)K + scol];
  const u16* Ag1 = Ag0 + 16 * (long)K;
  const u16* Wg0 = &W[(bn + srow) * (long)K + scol];
  const u16* Wg1 = Wg0 + 16 * (long)K;
  u16* Al0 = As + (w * 32) * 32;
  u16* Al1 = Al0 + 16 * 32;
  u16* Wl0 = Ws + (w * 32) * 32;
  u16* Wl1 = Wl0 + 16 * 32;

#pragma unroll
  for (int i = 0; i < 4; i++)
#pragma unroll
    for (int j = 0; j < 4; j++) acc[i][j] = f32x4{0.f, 0.f, 0.f, 0.f};

  for (int k0 = 0; k0 < K; k0 += 32) {
    gll16(Ag0 + k0, Al0);
    gll16(Ag1 + k0, Al1);
    gll16(Wg0 + k0, Wl0);
    gll16(Wg1 + k0, Wl1);
    __syncthreads();
    bf16x8 af[4], wf[4];
#pragma unroll
    for (int i = 0; i < 4; i++) af[i] = *(const bf16x8*)&As[(wm + i * 16 + cc) * 32 + kg8];
#pragma unroll
    for (int j = 0; j < 4; j++) wf[j] = *(const bf16x8*)&Ws[(wn + j * 16 + cc) * 32 + kg8];
#pragma unroll
    for (int i = 0; i < 4; i++)
#pragma unroll
      for (int j = 0; j < 4; j++)
        acc[i][j] = __builtin_amdgcn_mfma_f32_16x16x32_bf16(af[i], wf[j], acc[i][j], 0, 0, 0);
    __syncthreads();
  }
}

// ---------------- GEMM1: qkv projection + routing epilogue ----------------
__global__ __launch_bounds__(256) void gemm_qkv_kernel(
    const u16* __restrict__ A, const u16* __restrict__ W,
    u16* __restrict__ Qb, u16* __restrict__ Kb, u16* __restrict__ VTb) {
  __shared__ __align__(16) u16 As[128 * 32];
  __shared__ __align__(16) u16 Ws[128 * 32];
  f32x4 acc[4][4];
  gemm_core(A, W, 1024, acc, As, Ws);
  const int t = threadIdx.x, lane = t & 63, w = t >> 6;
  const int wm = (w >> 1) * 64, wn = (w & 1) * 64;
  const int bm = blockIdx.x * 128, bn = blockIdx.y * 128;
  const int rr = (lane >> 4) * 4, cc = lane & 15;
#pragma unroll
  for (int i = 0; i < 4; i++)
#pragma unroll
    for (int jf = 0; jf < 4; jf++)
#pragma unroll
      for (int j = 0; j < 4; j++) {
        int m = bm + wm + i * 16 + rr + j;
        int n = bn + wn + jf * 16 + cc;
        float v = acc[i][jf][j];
        if (n < 1024) {
          Qb[(long)m * 1024 + n] = f2bf(v * 0.18033688011112043f);  // 0.125*log2(e)
        } else {
          int c = n - 1024, g = c >> 7, rm = c & 127;
          int b = m >> 11, pos = m & 2047;
          long base = (long)(b * 4 + g);
          if (rm < 64) Kb[(base * 2048 + pos) * 64 + rm] = f2bf(v);
          else         VTb[(base * 64 + (rm - 64)) * 2048 + pos] = f2bf(v);
        }
      }
}

// ---------------- GEMM2: output projection, fp32 out ----------------
__global__ __launch_bounds__(256) void gemm_out_kernel(
    const u16* __restrict__ A, const u16* __restrict__ W, float* __restrict__ out) {
  __shared__ __align__(16) u16 As[128 * 32];
  __shared__ __align__(16) u16 Ws[128 * 32];
  f32x4 acc[4][4];
  gemm_core(A, W, 1024, acc, As, Ws);
  const int t = threadIdx.x, lane = t & 63, w = t >> 6;
  const int wm = (w >> 1) * 64, wn = (w & 1) * 64;
  const int bm = blockIdx.x * 128, bn = blockIdx.y * 128;
  const int rr = (lane >> 4) * 4, cc = lane & 15;
#pragma unroll
  for (int i = 0; i < 4; i++)
#pragma unroll
    for (int jf = 0; jf < 4; jf++)
#pragma unroll
      for (int j = 0; j < 4; j++) {
        int m = bm + wm + i * 16 + rr + j;
        int n = bn + wn + jf * 16 + cc;
        out[(long)m * 1024 + n] = acc[i][jf][j];
      }
}

// ---------------- flash attention (causal + ALiBi, GQA) ----------------
// Swapped-operand 32x32x16, in-register softmax, descending keys + defer-max,
// two-phase combine (LDS 19.5KB). launch_bounds (256,4): VGPR cap 128 —
// (256,8) forced a 64-VGPR cap -> full spill to scratch, 2GB HBM traffic (R4).
__global__ __launch_bounds__(256, 4) void attn_kernel(
    const u16* __restrict__ Q, const u16* __restrict__ Kb,
    const u16* __restrict__ VTb, u16* __restrict__ AT) {
  __shared__ __align__(16) float Ol[4][32][36];
  __shared__ float ml[4][2][32];

  const int t = threadIdx.x, lane = t & 63, w = t >> 6;
  const int qt = 63 - (int)blockIdx.x;   // LPT: longest blocks first
  const int h = blockIdx.y, b = blockIdx.z;
  const int g = h >> 2;
  const int lam = lane & 31, hi = lane >> 5;
  const int qrow0 = qt * 32;
  const int kblocks = (qrow0 + 95) >> 6;

  const u16* Qrow = Q + ((long)(b * 2048 + qrow0 + lam)) * 1024 + h * 64 + hi * 8;
  bf16x8 qf0 = *(const bf16x8*)(Qrow);
  bf16x8 qf1 = *(const bf16x8*)(Qrow + 16);
  bf16x8 qf2 = *(const bf16x8*)(Qrow + 32);
  bf16x8 qf3 = *(const bf16x8*)(Qrow + 48);

  const u16* Kg = Kb  + ((long)(b * 4 + g)) * 2048 * 64;
  const u16* Vg = VTb + ((long)(b * 4 + g)) * 64 * 2048;

  f32x16 zv;
#pragma unroll
  for (int i = 0; i < 16; i++) zv[i] = 0.f;
  f32x16 acc0 = zv, acc1 = zv;
  float m = -1e30f, lsum = 0.f;

  const float slope2 = exp2f(-0.5f * (float)(h + 1)) * 1.44269504f;
  const float fqr = (float)(qrow0 + lam);

  auto qk_tile = [&](int koff) -> f32x16 {
    const u16* Ka = Kg + (long)(koff + lam) * 64 + hi * 8;
    bf16x8 k0 = *(const bf16x8*)(Ka);
    bf16x8 k1 = *(const bf16x8*)(Ka + 16);
    bf16x8 k2 = *(const bf16x8*)(Ka + 32);
    bf16x8 k3 = *(const bf16x8*)(Ka + 48);
    f32x16 s = zv;
    s = __builtin_amdgcn_mfma_f32_32x32x16_bf16(k0, qf0, s, 0, 0, 0);
    s = __builtin_amdgcn_mfma_f32_32x32x16_bf16(k1, qf1, s, 0, 0, 0);
    s = __builtin_amdgcn_mfma_f32_32x32x16_bf16(k2, qf2, s, 0, 0, 0);
    s = __builtin_amdgcn_mfma_f32_32x32x16_bf16(k3, qf3, s, 0, 0, 0);
    float kb0 = (float)(koff + 4 * hi) - fqr;
    if (koff + 31 > qrow0) {
#pragma unroll
      for (int r = 0; r < 16; r++) {
        float d = kb0 + (float)((r & 3) + 8 * (r >> 2));
        s[r] = (d > 0.f) ? -1e30f : s[r] + slope2 * d;
      }
    } else {
#pragma unroll
      for (int r = 0; r < 16; r++)
        s[r] += slope2 * (kb0 + (float)((r & 3) + 8 * (r >> 2)));
    }
    return s;
  };

  auto pv_tile = [&](const f32x16 &p, int koff) {
    u32 wd[8];
#pragma unroll
    for (int i = 0; i < 8; i++) wd[i] = pk2bf(p[2 * i], p[2 * i + 1]);
    plswap(wd[0], wd[2]); plswap(wd[1], wd[3]);
    plswap(wd[4], wd[6]); plswap(wd[5], wd[7]);
    bf16x8 pf0 = __builtin_bit_cast(bf16x8, u32x4{wd[0], wd[1], wd[2], wd[3]});
    bf16x8 pf1 = __builtin_bit_cast(bf16x8, u32x4{wd[4], wd[5], wd[6], wd[7]});
    const u16* Va = Vg + (long)lam * 2048 + koff + hi * 8;
    bf16x8 v00 = *(const bf16x8*)(Va);
    bf16x8 v01 = *(const bf16x8*)(Va + 16);
    bf16x8 v10 = *(const bf16x8*)(Va + 32 * 2048);
    bf16x8 v11 = *(const bf16x8*)(Va + 32 * 2048 + 16);
    acc0 = __builtin_amdgcn_mfma_f32_32x32x16_bf16(v00, pf0, acc0, 0, 0, 0);
    acc0 = __builtin_amdgcn_mfma_f32_32x32x16_bf16(v01, pf1, acc0, 0, 0, 0);
    acc1 = __builtin_amdgcn_mfma_f32_32x32x16_bf16(v10, pf0, acc1, 0, 0, 0);
    acc1 = __builtin_amdgcn_mfma_f32_32x32x16_bf16(v11, pf1, acc1, 0, 0, 0);
  };

  const int jb0 = (kblocks > w) ? (w + (((kblocks - 1 - w) >> 2) << 2)) : -1;
  for (int jb = jb0; jb >= 0; jb -= 4) {
    const int kbase = jb * 64;
    f32x16 st0 = qk_tile(kbase);
    f32x16 st1;
    const bool t1v = (kbase + 32 <= qrow0 + 31);
    if (t1v) {
      st1 = qk_tile(kbase + 32);
    } else {
#pragma unroll
      for (int r = 0; r < 16; r++) st1[r] = -1e30f;
    }

    float red[8];
#pragma unroll
    for (int i = 0; i < 8; i++)
      red[i] = fmaxf(fmaxf(st0[i], st0[i + 8]), fmaxf(st1[i], st1[i + 8]));
#pragma unroll
    for (int i = 0; i < 4; i++) red[i] = fmaxf(red[i], red[i + 4]);
    float pm = fmaxf(fmaxf(red[0], red[1]), fmaxf(red[2], red[3]));
    pm = xhalf_max(pm);
    if (!__all(pm <= m + 8.f)) {       // T13 defer-max: P bounded by 2^8
      float mnew = fmaxf(m, pm);
      float al = exp2f(m - mnew);
      m = mnew;
      lsum *= al;
      acc0 *= al;
      acc1 *= al;
    }
#pragma unroll
    for (int r = 0; r < 16; r++) st0[r] = exp2f(st0[r] - m);
#pragma unroll
    for (int r = 0; r < 16; r++) st1[r] = exp2f(st1[r] - m);
    {
      float sr[8];
#pragma unroll
      for (int i = 0; i < 8; i++) sr[i] = (st0[i] + st0[i + 8]) + (st1[i] + st1[i + 8]);
#pragma unroll
      for (int i = 0; i < 4; i++) sr[i] += sr[i + 4];
      float rs = (sr[0] + sr[1]) + (sr[2] + sr[3]);
      lsum += xhalf_sum(rs);
    }

    pv_tile(st0, kbase);
    if (t1v) pv_tile(st1, kbase + 32);
  }

  // ---- two-phase cross-wave combine (halved LDS) ----
#pragma unroll
  for (int rq = 0; rq < 4; rq++)
    *(f32x4*)&Ol[w][lam][8 * rq + 4 * hi] =
        f32x4{acc0[4 * rq], acc0[4 * rq + 1], acc0[4 * rq + 2], acc0[4 * rq + 3]};
  if (hi == 0) { ml[w][0][lam] = m; ml[w][1][lam] = lsum; }
  __syncthreads();

  const int r = t >> 3, c0 = (t & 7) * 4;
  float M = fmaxf(fmaxf(ml[0][0][r], ml[1][0][r]), fmaxf(ml[2][0][r], ml[3][0][r]));
  float sc[4];
  float L = 0.f;
#pragma unroll
  for (int ww = 0; ww < 4; ww++) {
    sc[ww] = exp2f(ml[ww][0][r] - M);
    L += sc[ww] * ml[ww][1][r];
  }
  const float inv = 1.f / L;
  {
    float o[4] = {0.f, 0.f, 0.f, 0.f};
#pragma unroll
    for (int ww = 0; ww < 4; ww++)
#pragma unroll
      for (int i = 0; i < 4; i++) o[i] += sc[ww] * Ol[ww][r][c0 + i];
    uint2 ov;
    ov.x = ((u32)f2bf(o[1] * inv) << 16) | f2bf(o[0] * inv);
    ov.y = ((u32)f2bf(o[3] * inv) << 16) | f2bf(o[2] * inv);
    *(uint2*)&AT[((long)(b * 2048 + qrow0 + r)) * 1024 + h * 64 + c0] = ov;
  }
  __syncthreads();   // Ol reads done; safe to overwrite with acc1
#pragma unroll
  for (int rq = 0; rq < 4; rq++)
    *(f32x4*)&Ol[w][lam][8 * rq + 4 * hi] =
        f32x4{acc1[4 * rq], acc1[4 * rq + 1], acc1[4 * rq + 2], acc1[4 * rq + 3]};
  __syncthreads();
  {
    float o[4] = {0.f, 0.f, 0.f, 0.f};
#pragma unroll
    for (int ww = 0; ww < 4; ww++)
#pragma unroll
      for (int i = 0; i < 4; i++) o[i] += sc[ww] * Ol[ww][r][c0 + i];
    uint2 ov;
    ov.x = ((u32)f2bf(o[1] * inv) << 16) | f2bf(o[0] * inv);
    ov.y = ((u32)f2bf(o[3] * inv) << 16) | f2bf(o[2] * inv);
    *(uint2*)&AT[((long)(b * 2048 + qrow0 + r)) * 1024 + h * 64 + 32 + c0] = ov;
  }
}

// ---------------- launcher ----------------
extern "C" void kernel_launch(void* const* d_in, const int* in_sizes, int n_in,
                              void* d_out, int out_size, void* d_ws, size_t ws_size,
                              hipStream_t stream) {
  const float* x   = (const float*)d_in[0];
  const float* Wq  = (const float*)d_in[1];
  const float* Wkv = (const float*)d_in[2];
  const float* Wo  = (const float*)d_in[3];
  float* out = (float*)d_out;
  char* ws = (char*)d_ws;

  u16* xb    = (u16*)(ws);
  u16* wqkvb = (u16*)(ws + 8388608);
  u16* wob   = (u16*)(ws + 11534336);
  u16* Qb    = (u16*)(ws + 13631488);
  u16* Kb    = (u16*)(ws + 22020096);
  u16* VTb   = (u16*)(ws + 24117248);
  u16* AT    = (u16*)(ws + 26214400);

  cvt_kernel<<<6656, 256, 0, stream>>>(
      (const float4*)x, (const float4*)Wq, (const float4*)Wkv, (const float4*)Wo,
      (uint2*)xb, (uint2*)wqkvb, (uint2*)wob);

  gemm_qkv_kernel<<<dim3(32, 12), 256, 0, stream>>>(xb, wqkvb, Qb, Kb, VTb);

  attn_kernel<<<dim3(64, 16, 2), 256, 0, stream>>>(Qb, Kb, VTb, AT);

  gemm_out_kernel<<<dim3(32, 8), 256, 0, stream>>>(AT, wob, out);
}